// Round 1
// baseline (334.779 us; speedup 1.0000x reference)
//
#include <hip/hip_runtime.h>
#include <hip/hip_bf16.h>

#define S     4096
#define D     512
#define KWIN  3
#define MAXOUT 16384
#define EPSLN 1e-5f

// ---------------------------------------------------------------------------
// Weight transpose: w[o][i][k] (o*D*3 + i*3 + k) -> Bt[(k*D+i)*D + o]
// so conv becomes C = im2col(X) @ Bt with row-major Bt [3*D, D].
// ---------------------------------------------------------------------------
__global__ __launch_bounds__(256) void wtrans_kernel(const float* __restrict__ w,
                                                     float* __restrict__ Bt) {
  int t = blockIdx.x * 256 + threadIdx.x;         // over 3*D*D
  if (t >= KWIN * D * D) return;
  int o  = t % D;
  int kk = t / D;           // k*D + i
  int i  = kk % D;
  int k  = kk / D;
  Bt[t] = w[o * (D * KWIN) + i * KWIN + k];
}

// ---------------------------------------------------------------------------
// Conv-as-GEMM: C[4096,512] = A[4096,1536] @ Bt[1536,512] + bias[col]
// A is the virtual im2col of X: A[s, k*D+i] = (0<=s+k-1<S) ? X[s+k-1, i] : 0
// 64x64 block tile, BK=16, 256 threads, 4x4 microtile per thread.
// Since D/BK = 32 exactly, a K-tile never crosses a k-segment boundary.
// ---------------------------------------------------------------------------
#define BM 64
#define BN 64
#define BK 16
#define NKT (KWIN * D / BK)   // 96

__global__ __launch_bounds__(256) void gemm_conv_kernel(
    const float* __restrict__ X, const float* __restrict__ Bt,
    const float* __restrict__ bias, float* __restrict__ C) {
  __shared__ __align__(16) float As[BK][BM + 4];  // +4 pad: conflict-free col writes, keeps 16B row align
  __shared__ __align__(16) float Bs[BK][BN];

  const int tid  = threadIdx.x;
  const int row0 = blockIdx.x * BM;
  const int col0 = blockIdx.y * BN;

  // A staging: 64 rows x 16 cols, one float4 per thread
  const int a_r = tid >> 2;          // 0..63
  const int a_c = (tid & 3) << 2;    // 0,4,8,12
  // B staging: 16 rows x 64 cols, one float4 per thread
  const int b_r = tid >> 4;          // 0..15
  const int b_c = (tid & 15) << 2;   // 0..60

  const int tx = tid & 15;           // 0..15 -> 4 cols each
  const int ty = tid >> 4;           // 0..15 -> 4 rows each

  float acc[4][4] = {};

  for (int kt = 0; kt < NKT; ++kt) {
    const int kseg = kt >> 5;                 // 0,1,2 (tap index)
    const int i0   = (kt & 31) << 4;          // channel offset within tap
    const int g    = row0 + a_r + kseg - 1;   // padded row index

    float4 av = make_float4(0.f, 0.f, 0.f, 0.f);
    if (g >= 0 && g < S)
      av = *(const float4*)(X + (size_t)g * D + i0 + a_c);
    const float4 bv =
        *(const float4*)(Bt + (size_t)(kt * BK + b_r) * D + col0 + b_c);

    __syncthreads();   // previous tile's reads done before overwrite
    As[a_c + 0][a_r] = av.x;
    As[a_c + 1][a_r] = av.y;
    As[a_c + 2][a_r] = av.z;
    As[a_c + 3][a_r] = av.w;
    *(float4*)&Bs[b_r][b_c] = bv;
    __syncthreads();

#pragma unroll
    for (int kk = 0; kk < BK; ++kk) {
      const float4 a = *(const float4*)&As[kk][ty << 2];
      const float4 b = *(const float4*)&Bs[kk][tx << 2];
      const float am[4] = {a.x, a.y, a.z, a.w};
      const float bm[4] = {b.x, b.y, b.z, b.w};
#pragma unroll
      for (int j = 0; j < 4; ++j)
#pragma unroll
        for (int jj = 0; jj < 4; ++jj)
          acc[j][jj] = fmaf(am[j], bm[jj], acc[j][jj]);
    }
  }

  const float4 bb = *(const float4*)(bias + col0 + (tx << 2));
#pragma unroll
  for (int j = 0; j < 4; ++j) {
    const int r = row0 + (ty << 2) + j;
    float4 o;
    o.x = acc[j][0] + bb.x;
    o.y = acc[j][1] + bb.y;
    o.z = acc[j][2] + bb.z;
    o.w = acc[j][3] + bb.w;
    *(float4*)(C + (size_t)r * D + col0 + (tx << 2)) = o;
  }
}

// ---------------------------------------------------------------------------
// LayerNorm (population var, eps inside rsqrt) + ReLU. One row per block.
// ---------------------------------------------------------------------------
__global__ __launch_bounds__(512) void ln_relu_kernel(
    const float* __restrict__ X, const float* __restrict__ g,
    const float* __restrict__ b, float* __restrict__ Y) {
  __shared__ float red[512];
  const int row = blockIdx.x;
  const int tid = threadIdx.x;
  const float x = X[(size_t)row * D + tid];

  red[tid] = x;
  __syncthreads();
#pragma unroll
  for (int s2 = 256; s2 > 0; s2 >>= 1) {
    if (tid < s2) red[tid] += red[tid + s2];
    __syncthreads();
  }
  const float m = red[0] * (1.0f / D);
  __syncthreads();

  const float dx = x - m;
  red[tid] = dx * dx;
  __syncthreads();
#pragma unroll
  for (int s2 = 256; s2 > 0; s2 >>= 1) {
    if (tid < s2) red[tid] += red[tid + s2];
    __syncthreads();
  }
  const float v = red[0] * (1.0f / D);

  const float y = dx * rsqrtf(v + EPSLN) * g[tid] + b[tid];
  Y[(size_t)row * D + tid] = fmaxf(y, 0.0f);
}

// ---------------------------------------------------------------------------
// pred[s] = relu(dot(x2[s,:], lw) + lb); dur[s] = (int)floor(pred + 0.5)
// One wave (64 lanes) per row, 8 elements/lane via two float4s.
// ---------------------------------------------------------------------------
__global__ __launch_bounds__(256) void pred_dur_kernel(
    const float* __restrict__ X2, const float* __restrict__ lw,
    const float* __restrict__ lb, int* __restrict__ dur) {
  const int wave = threadIdx.x >> 6;
  const int lane = threadIdx.x & 63;
  const int row  = blockIdx.x * 4 + wave;
  const float4 x0 = *(const float4*)(X2 + (size_t)row * D + (lane << 2));
  const float4 x1 = *(const float4*)(X2 + (size_t)row * D + 256 + (lane << 2));
  const float4 w0 = *(const float4*)(lw + (lane << 2));
  const float4 w1 = *(const float4*)(lw + 256 + (lane << 2));
  float s = x0.x * w0.x + x0.y * w0.y + x0.z * w0.z + x0.w * w0.w +
            x1.x * w1.x + x1.y * w1.y + x1.z * w1.z + x1.w * w1.w;
#pragma unroll
  for (int off = 32; off > 0; off >>= 1) s += __shfl_down(s, off);
  if (lane == 0) {
    const float p = fmaxf(s + lb[0], 0.0f);
    dur[row] = (int)floorf(p + 0.5f);
  }
}

// ---------------------------------------------------------------------------
// Inclusive scan of 4096 int durations. Single block, 1024 threads x 4 elems.
// ---------------------------------------------------------------------------
__global__ __launch_bounds__(1024) void scan_kernel(const int* __restrict__ dur,
                                                    int* __restrict__ cum) {
  __shared__ int sd[1024];
  const int tid = threadIdx.x;
  const int4 d = *(const int4*)(dur + (tid << 2));
  const int l0 = d.x;
  const int l1 = l0 + d.y;
  const int l2 = l1 + d.z;
  const int l3 = l2 + d.w;
  sd[tid] = l3;
  __syncthreads();
  for (int off = 1; off < 1024; off <<= 1) {
    int v = 0;
    if (tid >= off) v = sd[tid - off];
    __syncthreads();
    sd[tid] += v;
    __syncthreads();
  }
  const int base = (tid > 0) ? sd[tid - 1] : 0;
  int4 o;
  o.x = base + l0; o.y = base + l1; o.z = base + l2; o.w = base + l3;
  *(int4*)(cum + (tid << 2)) = o;
}

// ---------------------------------------------------------------------------
// Length-regulate: for each frame t, idx = searchsorted(cum, t, 'right'),
// out0[t,:] = (t < cum[S-1]) ? enc[min(idx,S-1),:] : 0.  out1[t] = t+1 (float).
// 2 frames per 256-thread block; 128 lanes x float4 = 512 floats per frame.
// ---------------------------------------------------------------------------
__global__ __launch_bounds__(256) void gather_kernel(
    const float* __restrict__ enc, const int* __restrict__ cum,
    float* __restrict__ out0, float* __restrict__ out1) {
  const int half = threadIdx.x >> 7;              // 0/1
  const int d4   = (threadIdx.x & 127) << 2;      // 0..508
  const int t    = blockIdx.x * 2 + half;
  const int total = cum[S - 1];

  int lo = 0, hi = S;
  while (lo < hi) {
    const int mid = (lo + hi) >> 1;
    if (cum[mid] <= t) lo = mid + 1; else hi = mid;
  }
  const int idx = (lo < S) ? lo : (S - 1);

  float4 v = make_float4(0.f, 0.f, 0.f, 0.f);
  if (t < total) v = *(const float4*)(enc + (size_t)idx * D + d4);
  *(float4*)(out0 + (size_t)t * D + d4) = v;

  if ((threadIdx.x & 127) == 0) out1[t] = (float)(t + 1);
}

// ---------------------------------------------------------------------------
extern "C" void kernel_launch(void* const* d_in, const int* in_sizes, int n_in,
                              void* d_out, int out_size, void* d_ws, size_t ws_size,
                              hipStream_t stream) {
  const float* enc = (const float*)d_in[0];
  const float* w1  = (const float*)d_in[1];
  const float* cb1 = (const float*)d_in[2];
  const float* g1  = (const float*)d_in[3];
  const float* be1 = (const float*)d_in[4];
  const float* w2  = (const float*)d_in[5];
  const float* cb2 = (const float*)d_in[6];
  const float* g2  = (const float*)d_in[7];
  const float* be2 = (const float*)d_in[8];
  const float* lw  = (const float*)d_in[9];
  const float* lb  = (const float*)d_in[10];

  float* out0 = (float*)d_out;                      // [16384, 512]
  float* out1 = out0 + (size_t)MAXOUT * D;          // [16384] as float

  // Workspace layout (all 16B-aligned): Bt 3MB | t0 8MB | t1 8MB | dur | cum
  char* ws = (char*)d_ws;
  float* Bt = (float*)ws;                                   // 3*D*D floats
  float* t0 = (float*)(ws + (size_t)3 * D * D * 4);         // S*D
  float* t1 = t0 + (size_t)S * D;                           // S*D
  int*  dur = (int*)(t1 + (size_t)S * D);
  int*  cum = dur + S;

  const int ntrans = KWIN * D * D;

  wtrans_kernel<<<(ntrans + 255) / 256, 256, 0, stream>>>(w1, Bt);
  gemm_conv_kernel<<<dim3(S / BM, D / BN), 256, 0, stream>>>(enc, Bt, cb1, t0);
  ln_relu_kernel<<<S, 512, 0, stream>>>(t0, g1, be1, t1);

  wtrans_kernel<<<(ntrans + 255) / 256, 256, 0, stream>>>(w2, Bt);
  gemm_conv_kernel<<<dim3(S / BM, D / BN), 256, 0, stream>>>(t1, Bt, cb2, t0);
  ln_relu_kernel<<<S, 512, 0, stream>>>(t0, g2, be2, t1);

  pred_dur_kernel<<<S / 4, 256, 0, stream>>>(t1, lw, lb, dur);
  scan_kernel<<<1, 1024, 0, stream>>>(dur, cum);
  gather_kernel<<<MAXOUT / 2, 256, 0, stream>>>(enc, cum, out0, out1);
}

// Round 2
// 203.124 us; speedup vs baseline: 1.6481x; 1.6481x over previous
//
#include <hip/hip_runtime.h>

#define S      4096
#define D      512
#define KWIN   3
#define SP     (S + 2)          // zero-padded rows: g = s + tap, g in [0, S+1]
#define MAXOUT 16384
#define EPSLN  1e-5f
#define NIT    16               // i-tiles per tap (512/32)
#define NKT    48               // total K tiles (1536/32)

typedef __attribute__((ext_vector_type(8))) short short8;
typedef __attribute__((ext_vector_type(4))) float floatx4;

__device__ inline ushort f2bf(float x) {
  union { float f; unsigned u; } v; v.f = x;
  unsigned r = v.u + 0x7fffu + ((v.u >> 16) & 1u);
  return (ushort)(r >> 16);
}
__device__ inline float bf2f(ushort h) {
  union { float f; unsigned u; } v; v.u = ((unsigned)h) << 16;
  return v.f;
}

// ---------------------------------------------------------------------------
// enc [S][D] fp32 -> packed bf16 hi/lo [NIT][SP][32], pad rows (g=0, SP-1) = 0
// ---------------------------------------------------------------------------
__global__ __launch_bounds__(256) void pack_x_kernel(const float* __restrict__ x,
                                                     ushort* __restrict__ ph,
                                                     ushort* __restrict__ pl) {
  int t = blockIdx.x * 256 + threadIdx.x;      // over SP*D
  if (t >= SP * D) return;
  int g = t >> 9;
  int i = t & 511;
  float v = (g == 0 || g == SP - 1) ? 0.0f : x[(size_t)(g - 1) * D + i];
  ushort hi = f2bf(v);
  ushort lo = f2bf(v - bf2f(hi));
  size_t dst = ((size_t)(i >> 5) * SP + g) * 32 + (i & 31);
  ph[dst] = hi;
  pl[dst] = lo;
}

// ---------------------------------------------------------------------------
// Zero the pad rows of the T1 packed arrays (LN kernel writes rows 1..S only).
// ---------------------------------------------------------------------------
__global__ __launch_bounds__(256) void t1pad_kernel(ushort* __restrict__ th,
                                                    ushort* __restrict__ tl) {
  for (int idx = threadIdx.x; idx < NIT * 2 * 32; idx += 256) {
    int c   = idx >> 6;
    int rr  = (idx >> 5) & 1;
    int col = idx & 31;
    size_t off = ((size_t)c * SP + (rr ? (SP - 1) : 0)) * 32 + col;
    th[off] = 0;
    tl[off] = 0;
  }
}

// ---------------------------------------------------------------------------
// w [D][D][KWIN] fp32 -> packed bf16 hi/lo Bp[kt][o][kk], kt = k*NIT + i/32,
// kk = i%32.  Reads coalesced (w[t]); writes scattered 2B (L2-absorbed).
// ---------------------------------------------------------------------------
__global__ __launch_bounds__(256) void wtrans_pack_kernel(const float* __restrict__ w,
                                                          ushort* __restrict__ bh,
                                                          ushort* __restrict__ bl) {
  int t = blockIdx.x * 256 + threadIdx.x;   // over D*D*KWIN
  if (t >= D * D * KWIN) return;
  float v = w[t];
  int o   = t / (D * KWIN);
  int rem = t - o * (D * KWIN);
  int i   = rem / KWIN;
  int k   = rem - i * KWIN;
  ushort hi = f2bf(v);
  ushort lo = f2bf(v - bf2f(hi));
  size_t dst = ((size_t)(k * NIT + (i >> 5)) * D + o) * 32 + (i & 31);
  bh[dst] = hi;
  bl[dst] = lo;
}

// ---------------------------------------------------------------------------
// MFMA GEMM: C[S][D] = im2col(A) @ B, fp32-accurate via bf16 hi/lo (3 products).
// 64x64 tile, BK=32, 4 waves; wave w owns the 32x32 quadrant (w>>1, w&1).
// A tiles: Ap[itile][row0+tap .. +63][32] contiguous 4 KB -> global_load_lds.
// B tiles: Bp[kt][col0 .. +63][32]       contiguous 4 KB -> global_load_lds.
// ---------------------------------------------------------------------------
__device__ inline void gload16(const void* g, void* l) {
  __builtin_amdgcn_global_load_lds((const __attribute__((address_space(1))) void*)g,
                                   (__attribute__((address_space(3))) void*)l,
                                   16, 0, 0);
}

__global__ __launch_bounds__(256) void gemm_mfma_kernel(
    const ushort* __restrict__ Ah, const ushort* __restrict__ Al,
    const ushort* __restrict__ Bh, const ushort* __restrict__ Bl,
    float* __restrict__ C) {
  __shared__ __align__(16) ushort Ahs[64 * 32];
  __shared__ __align__(16) ushort Als[64 * 32];
  __shared__ __align__(16) ushort Bhs[64 * 32];
  __shared__ __align__(16) ushort Bls[64 * 32];

  const int tid  = threadIdx.x;
  const int wave = tid >> 6;
  const int lane = tid & 63;
  const int row0 = blockIdx.x * 64;
  const int col0 = blockIdx.y * 64;
  const int wm0  = (wave >> 1) * 32;
  const int wn0  = (wave & 1) * 32;
  const int fr   = lane & 15;
  const int quad = lane >> 4;

  floatx4 acc[2][2] = {};

  ushort* sbase = (wave == 0) ? Ahs : (wave == 1) ? Als : (wave == 2) ? Bhs : Bls;

  for (int kt = 0; kt < NKT; ++kt) {
    const int tap   = kt >> 4;
    const int itile = kt & 15;
    const ushort* gb;
    if (wave == 0)      gb = Ah + ((size_t)itile * SP + row0 + tap) * 32;
    else if (wave == 1) gb = Al + ((size_t)itile * SP + row0 + tap) * 32;
    else if (wave == 2) gb = Bh + ((size_t)kt * D + col0) * 32;
    else                gb = Bl + ((size_t)kt * D + col0) * 32;

    __syncthreads();                       // prior iter's fragment reads done
#pragma unroll
    for (int seg = 0; seg < 4; ++seg)      // 4 x 1024B per wave = 4 KB tile
      gload16(gb + seg * 512 + lane * 8, sbase + seg * 512);
    asm volatile("s_waitcnt vmcnt(0)" ::: "memory");
    __syncthreads();                       // all 4 arrays staged

    short8 ah[2], al2[2], bh[2], bl2[2];
#pragma unroll
    for (int mf = 0; mf < 2; ++mf) {
      ah[mf]  = *(const short8*)&Ahs[(wm0 + mf * 16 + fr) * 32 + quad * 8];
      al2[mf] = *(const short8*)&Als[(wm0 + mf * 16 + fr) * 32 + quad * 8];
    }
#pragma unroll
    for (int nf = 0; nf < 2; ++nf) {
      bh[nf]  = *(const short8*)&Bhs[(wn0 + nf * 16 + fr) * 32 + quad * 8];
      bl2[nf] = *(const short8*)&Bls[(wn0 + nf * 16 + fr) * 32 + quad * 8];
    }
#pragma unroll
    for (int mf = 0; mf < 2; ++mf)
#pragma unroll
      for (int nf = 0; nf < 2; ++nf) {
        acc[mf][nf] = __builtin_amdgcn_mfma_f32_16x16x32_bf16(ah[mf],  bh[nf],  acc[mf][nf], 0, 0, 0);
        acc[mf][nf] = __builtin_amdgcn_mfma_f32_16x16x32_bf16(ah[mf],  bl2[nf], acc[mf][nf], 0, 0, 0);
        acc[mf][nf] = __builtin_amdgcn_mfma_f32_16x16x32_bf16(al2[mf], bh[nf],  acc[mf][nf], 0, 0, 0);
      }
  }

#pragma unroll
  for (int mf = 0; mf < 2; ++mf)
#pragma unroll
    for (int nf = 0; nf < 2; ++nf) {
      const int col = col0 + wn0 + nf * 16 + fr;
#pragma unroll
      for (int r = 0; r < 4; ++r) {
        const int row = row0 + wm0 + mf * 16 + quad * 4 + r;
        C[(size_t)row * D + col] = acc[mf][nf][r];
      }
    }
}

// ---------------------------------------------------------------------------
// (conv_out + conv_bias) -> LayerNorm -> ReLU -> bf16 hi/lo packed (row g=s+1).
// One wave per row, 8 cols/lane, shuffle all-reduce.
// ---------------------------------------------------------------------------
__global__ __launch_bounds__(256) void ln_relu_pack_kernel(
    const float* __restrict__ X, const float* __restrict__ cb,
    const float* __restrict__ gam, const float* __restrict__ bet,
    ushort* __restrict__ th, ushort* __restrict__ tl) {
  const int wave = threadIdx.x >> 6;
  const int lane = threadIdx.x & 63;
  const int s = blockIdx.x * 4 + wave;
  const float4* xp = (const float4*)(X + (size_t)s * D);
  float4 a = xp[2 * lane];
  float4 b = xp[2 * lane + 1];
  const float4 ca  = ((const float4*)cb)[2 * lane];
  const float4 cb2 = ((const float4*)cb)[2 * lane + 1];
  float v[8] = {a.x + ca.x,  a.y + ca.y,  a.z + ca.z,  a.w + ca.w,
                b.x + cb2.x, b.y + cb2.y, b.z + cb2.z, b.w + cb2.w};
  float sum = 0.f;
#pragma unroll
  for (int i = 0; i < 8; ++i) sum += v[i];
#pragma unroll
  for (int off = 32; off > 0; off >>= 1) sum += __shfl_xor(sum, off);
  const float m = sum * (1.0f / D);
  float sq = 0.f;
#pragma unroll
  for (int i = 0; i < 8; ++i) { v[i] -= m; sq += v[i] * v[i]; }
#pragma unroll
  for (int off = 32; off > 0; off >>= 1) sq += __shfl_xor(sq, off);
  const float rs = rsqrtf(sq * (1.0f / D) + EPSLN);
  const float4 ga = ((const float4*)gam)[2 * lane];
  const float4 gb = ((const float4*)gam)[2 * lane + 1];
  const float4 ba = ((const float4*)bet)[2 * lane];
  const float4 bb = ((const float4*)bet)[2 * lane + 1];
  const float gg[8] = {ga.x, ga.y, ga.z, ga.w, gb.x, gb.y, gb.z, gb.w};
  const float bt[8] = {ba.x, ba.y, ba.z, ba.w, bb.x, bb.y, bb.z, bb.w};
  short8 h8, l8;
#pragma unroll
  for (int i = 0; i < 8; ++i) {
    float y = fmaxf(v[i] * rs * gg[i] + bt[i], 0.0f);
    ushort hi = f2bf(y);
    h8[i] = (short)hi;
    l8[i] = (short)f2bf(y - bf2f(hi));
  }
  const size_t base = ((size_t)(lane >> 2) * SP + (s + 1)) * 32 + (size_t)(lane & 3) * 8;
  *(short8*)(th + base) = h8;
  *(short8*)(tl + base) = l8;
}

// ---------------------------------------------------------------------------
// (conv2_out + bias) -> LN -> ReLU -> dot(lw) -> relu -> dur = floor(p + 0.5)
// ---------------------------------------------------------------------------
__global__ __launch_bounds__(256) void ln2_pred_kernel(
    const float* __restrict__ X, const float* __restrict__ cb,
    const float* __restrict__ gam, const float* __restrict__ bet,
    const float* __restrict__ lw, const float* __restrict__ lb,
    int* __restrict__ dur) {
  const int wave = threadIdx.x >> 6;
  const int lane = threadIdx.x & 63;
  const int s = blockIdx.x * 4 + wave;
  const float4* xp = (const float4*)(X + (size_t)s * D);
  float4 a = xp[2 * lane];
  float4 b = xp[2 * lane + 1];
  const float4 ca  = ((const float4*)cb)[2 * lane];
  const float4 cb2 = ((const float4*)cb)[2 * lane + 1];
  float v[8] = {a.x + ca.x,  a.y + ca.y,  a.z + ca.z,  a.w + ca.w,
                b.x + cb2.x, b.y + cb2.y, b.z + cb2.z, b.w + cb2.w};
  float sum = 0.f;
#pragma unroll
  for (int i = 0; i < 8; ++i) sum += v[i];
#pragma unroll
  for (int off = 32; off > 0; off >>= 1) sum += __shfl_xor(sum, off);
  const float m = sum * (1.0f / D);
  float sq = 0.f;
#pragma unroll
  for (int i = 0; i < 8; ++i) { v[i] -= m; sq += v[i] * v[i]; }
#pragma unroll
  for (int off = 32; off > 0; off >>= 1) sq += __shfl_xor(sq, off);
  const float rs = rsqrtf(sq * (1.0f / D) + EPSLN);
  const float4 ga = ((const float4*)gam)[2 * lane];
  const float4 gb = ((const float4*)gam)[2 * lane + 1];
  const float4 ba = ((const float4*)bet)[2 * lane];
  const float4 bb = ((const float4*)bet)[2 * lane + 1];
  const float gg[8] = {ga.x, ga.y, ga.z, ga.w, gb.x, gb.y, gb.z, gb.w};
  const float bt[8] = {ba.x, ba.y, ba.z, ba.w, bb.x, bb.y, bb.z, bb.w};
  const float4 w0 = ((const float4*)lw)[2 * lane];
  const float4 w1 = ((const float4*)lw)[2 * lane + 1];
  const float ww[8] = {w0.x, w0.y, w0.z, w0.w, w1.x, w1.y, w1.z, w1.w};
  float d = 0.f;
#pragma unroll
  for (int i = 0; i < 8; ++i) {
    float y = fmaxf(v[i] * rs * gg[i] + bt[i], 0.0f);
    d += y * ww[i];
  }
#pragma unroll
  for (int off = 32; off > 0; off >>= 1) d += __shfl_xor(d, off);
  if (lane == 0) {
    const float p = fmaxf(d + lb[0], 0.0f);
    dur[s] = (int)floorf(p + 0.5f);
  }
}

// ---------------------------------------------------------------------------
// Inclusive scan of S int durations. Single block, 1024 threads x 4 elems.
// ---------------------------------------------------------------------------
__global__ __launch_bounds__(1024) void scan_kernel(const int* __restrict__ dur,
                                                    int* __restrict__ cum) {
  __shared__ int sd[1024];
  const int tid = threadIdx.x;
  const int4 d = *(const int4*)(dur + (tid << 2));
  const int l0 = d.x;
  const int l1 = l0 + d.y;
  const int l2 = l1 + d.z;
  const int l3 = l2 + d.w;
  sd[tid] = l3;
  __syncthreads();
  for (int off = 1; off < 1024; off <<= 1) {
    int v = 0;
    if (tid >= off) v = sd[tid - off];
    __syncthreads();
    sd[tid] += v;
    __syncthreads();
  }
  const int base = (tid > 0) ? sd[tid - 1] : 0;
  int4 o;
  o.x = base + l0; o.y = base + l1; o.z = base + l2; o.w = base + l3;
  *(int4*)(cum + (tid << 2)) = o;
}

// ---------------------------------------------------------------------------
// Length-regulate gather. 2 frames per 256-thread block.
// ---------------------------------------------------------------------------
__global__ __launch_bounds__(256) void gather_kernel(
    const float* __restrict__ enc, const int* __restrict__ cum,
    float* __restrict__ out0, float* __restrict__ out1) {
  const int half = threadIdx.x >> 7;
  const int d4   = (threadIdx.x & 127) << 2;
  const int t    = blockIdx.x * 2 + half;
  const int total = cum[S - 1];

  int lo = 0, hi = S;
  while (lo < hi) {
    const int mid = (lo + hi) >> 1;
    if (cum[mid] <= t) lo = mid + 1; else hi = mid;
  }
  const int idx = (lo < S) ? lo : (S - 1);

  float4 v = make_float4(0.f, 0.f, 0.f, 0.f);
  if (t < total) v = *(const float4*)(enc + (size_t)idx * D + d4);
  *(float4*)(out0 + (size_t)t * D + d4) = v;

  if ((threadIdx.x & 127) == 0) out1[t] = (float)(t + 1);
}

// ---------------------------------------------------------------------------
extern "C" void kernel_launch(void* const* d_in, const int* in_sizes, int n_in,
                              void* d_out, int out_size, void* d_ws, size_t ws_size,
                              hipStream_t stream) {
  const float* enc = (const float*)d_in[0];
  const float* w1  = (const float*)d_in[1];
  const float* cb1 = (const float*)d_in[2];
  const float* g1  = (const float*)d_in[3];
  const float* be1 = (const float*)d_in[4];
  const float* w2  = (const float*)d_in[5];
  const float* cb2 = (const float*)d_in[6];
  const float* g2  = (const float*)d_in[7];
  const float* be2 = (const float*)d_in[8];
  const float* lw  = (const float*)d_in[9];
  const float* lb  = (const float*)d_in[10];

  float* out0 = (float*)d_out;                 // [MAXOUT, D]
  float* out1 = out0 + (size_t)MAXOUT * D;     // [MAXOUT]

  // ws: Xph | Xpl | T1h | T1l | Bph | Bpl | t0 | dur | cum   (~28.3 MB)
  const size_t NP = (size_t)NIT * SP * 32;     // packed activation elems
  const size_t NB = (size_t)NKT * D * 32;      // packed weight elems
  ushort* Xph = (ushort*)d_ws;
  ushort* Xpl = Xph + NP;
  ushort* T1h = Xpl + NP;
  ushort* T1l = T1h + NP;
  ushort* Bph = T1l + NP;
  ushort* Bpl = Bph + NB;
  float*  t0  = (float*)(Bpl + NB);            // S*D fp32
  int*   dur  = (int*)(t0 + (size_t)S * D);
  int*   cum  = dur + S;

  pack_x_kernel<<<(SP * D + 255) / 256, 256, 0, stream>>>(enc, Xph, Xpl);
  t1pad_kernel<<<1, 256, 0, stream>>>(T1h, T1l);
  wtrans_pack_kernel<<<(D * D * KWIN + 255) / 256, 256, 0, stream>>>(w1, Bph, Bpl);
  gemm_mfma_kernel<<<dim3(S / 64, D / 64), 256, 0, stream>>>(Xph, Xpl, Bph, Bpl, t0);
  ln_relu_pack_kernel<<<S / 4, 256, 0, stream>>>(t0, cb1, g1, be1, T1h, T1l);
  wtrans_pack_kernel<<<(D * D * KWIN + 255) / 256, 256, 0, stream>>>(w2, Bph, Bpl);
  gemm_mfma_kernel<<<dim3(S / 64, D / 64), 256, 0, stream>>>(T1h, T1l, Bph, Bpl, t0);
  ln2_pred_kernel<<<S / 4, 256, 0, stream>>>(t0, cb2, g2, be2, lw, lb, dur);
  scan_kernel<<<1, 1024, 0, stream>>>(dur, cum);
  gather_kernel<<<MAXOUT / 2, 256, 0, stream>>>(enc, cum, out0, out1);
}

// Round 3
// 165.056 us; speedup vs baseline: 2.0283x; 1.2306x over previous
//
#include <hip/hip_runtime.h>

#define S      4096
#define D      512
#define KWIN   3
#define SP     (S + 2)          // zero-padded rows: g = s + tap, g in [0, S+1]
#define MAXOUT 16384
#define EPSLN  1e-5f
#define NIT    16               // i-tiles per tap (512/32)
#define NKT    48               // total K tiles (1536/32)
#define NPAIR  24               // BK=64 pairs

typedef __attribute__((ext_vector_type(8))) short short8;
typedef __attribute__((ext_vector_type(4))) float floatx4;

__device__ inline ushort f2bf(float x) {
  union { float f; unsigned u; } v; v.f = x;
  unsigned r = v.u + 0x7fffu + ((v.u >> 16) & 1u);
  return (ushort)(r >> 16);
}
__device__ inline float bf2f(ushort h) {
  union { float f; unsigned u; } v; v.u = ((unsigned)h) << 16;
  return v.f;
}

// ---------------------------------------------------------------------------
// One launch does ALL packing:
//  region 0: enc [S][D] -> Xp hi/lo [NIT][SP][32] with zero pad rows
//  region 1: w1 -> Bp1 hi/lo (output-indexed, coalesced writes)
//  region 2: w2 -> Bp2 hi/lo
//  region 3: zero T1 pad rows
// ---------------------------------------------------------------------------
#define NB0 8196                 // SP*D/256
#define NB1 3072                 // 48*512*32/256
#define NB3 4

__device__ inline void wpack(const float* __restrict__ w, ushort* __restrict__ bh,
                             ushort* __restrict__ bl, int idx) {
  const int kk = idx & 31;
  const int o  = (idx >> 5) & 511;
  const int it = (idx >> 14) & 15;
  const int k  = idx >> 18;
  const float v = w[o * (D * KWIN) + (it * 32 + kk) * KWIN + k];
  const ushort hi = f2bf(v);
  bh[idx] = hi;
  bl[idx] = f2bf(v - bf2f(hi));
}

__global__ __launch_bounds__(256) void pack_all_kernel(
    const float* __restrict__ x, const float* __restrict__ w1,
    const float* __restrict__ w2, ushort* __restrict__ Xph,
    ushort* __restrict__ Xpl, ushort* __restrict__ B1h, ushort* __restrict__ B1l,
    ushort* __restrict__ B2h, ushort* __restrict__ B2l,
    ushort* __restrict__ T1h, ushort* __restrict__ T1l) {
  const int b = blockIdx.x;
  if (b < NB0) {
    const int t = b * 256 + threadIdx.x;        // over SP*D
    const int g = t >> 9;
    const int i = t & 511;
    const float v = (g == 0 || g == SP - 1) ? 0.0f : x[(size_t)(g - 1) * D + i];
    const ushort hi = f2bf(v);
    const size_t dst = ((size_t)(i >> 5) * SP + g) * 32 + (i & 31);
    Xph[dst] = hi;
    Xpl[dst] = f2bf(v - bf2f(hi));
  } else if (b < NB0 + NB1) {
    wpack(w1, B1h, B1l, (b - NB0) * 256 + threadIdx.x);
  } else if (b < NB0 + 2 * NB1) {
    wpack(w2, B2h, B2l, (b - NB0 - NB1) * 256 + threadIdx.x);
  } else {
    const int idx = (b - NB0 - 2 * NB1) * 256 + threadIdx.x;   // 0..1023
    const int c   = idx >> 6;
    const int rr  = (idx >> 5) & 1;
    const int col = idx & 31;
    const size_t off = ((size_t)c * SP + (rr ? (SP - 1) : 0)) * 32 + col;
    T1h[off] = 0;
    T1l[off] = 0;
  }
}

// ---------------------------------------------------------------------------
// MFMA GEMM, fp32-accurate via bf16 hi/lo (hh+hl+lh), double-buffered LDS.
// 64x64 tile, BK=64 (2 k-subtiles/iter), 4 waves; wave w stages array w and
// owns output quadrant (w>>1, w&1). One barrier per iteration; the
// compiler's vmcnt(0) at the barrier waits on loads issued one full compute
// phase earlier (prefetch distance 1).
// ---------------------------------------------------------------------------
__device__ inline void gload16(const void* g, void* l) {
  __builtin_amdgcn_global_load_lds((const __attribute__((address_space(1))) void*)g,
                                   (__attribute__((address_space(3))) void*)l,
                                   16, 0, 0);
}

__global__ __launch_bounds__(256) void gemm_mfma_kernel(
    const ushort* __restrict__ Ah, const ushort* __restrict__ Al,
    const ushort* __restrict__ Bh, const ushort* __restrict__ Bl,
    float* __restrict__ C) {
  // [dbuf][array: Ah,Al,Bh,Bl][sub][row*32]  = 64 KB total
  __shared__ __align__(16) ushort smem[2][4][2][2048];

  const int tid  = threadIdx.x;
  const int wave = tid >> 6;
  const int lane = tid & 63;
  const int row0 = blockIdx.x * 64;
  const int col0 = blockIdx.y * 64;
  const int wm0  = (wave >> 1) * 32;
  const int wn0  = (wave & 1) * 32;
  const int fr   = lane & 15;
  const int quad = lane >> 4;

  floatx4 acc[2][2] = {};

  // per-wave global tile base for k-tile kt (each tile 64 rows x 32 = 4 KB)
  auto gbase = [&](int kt) -> const ushort* {
    const int tap   = kt >> 4;
    const int itile = kt & 15;
    if (wave == 0)      return Ah + ((size_t)itile * SP + row0 + tap) * 32;
    else if (wave == 1) return Al + ((size_t)itile * SP + row0 + tap) * 32;
    else if (wave == 2) return Bh + ((size_t)kt * D + col0) * 32;
    else                return Bl + ((size_t)kt * D + col0) * 32;
  };

  auto stage = [&](int p, int db) {
    ushort* ldsb = &smem[db][wave][0][0];
#pragma unroll
    for (int sub = 0; sub < 2; ++sub) {
      const ushort* gb = gbase(2 * p + sub);
#pragma unroll
      for (int seg = 0; seg < 4; ++seg)
        gload16(gb + seg * 512 + lane * 8, ldsb + sub * 2048 + seg * 512);
    }
  };

  stage(0, 0);

  for (int p = 0; p < NPAIR; ++p) {
    const int db = p & 1;
    __syncthreads();                 // drains this buffer's loads (vmcnt(0))
    if (p + 1 < NPAIR) stage(p + 1, db ^ 1);

    const ushort* As_h = &smem[db][0][0][0];
    const ushort* As_l = &smem[db][1][0][0];
    const ushort* Bs_h = &smem[db][2][0][0];
    const ushort* Bs_l = &smem[db][3][0][0];
#pragma unroll
    for (int sub = 0; sub < 2; ++sub) {
      const int so = sub * 2048;
      short8 ah[2], al2[2], bh[2], bl2[2];
#pragma unroll
      for (int mf = 0; mf < 2; ++mf) {
        ah[mf]  = *(const short8*)&As_h[so + (wm0 + mf * 16 + fr) * 32 + quad * 8];
        al2[mf] = *(const short8*)&As_l[so + (wm0 + mf * 16 + fr) * 32 + quad * 8];
      }
#pragma unroll
      for (int nf = 0; nf < 2; ++nf) {
        bh[nf]  = *(const short8*)&Bs_h[so + (wn0 + nf * 16 + fr) * 32 + quad * 8];
        bl2[nf] = *(const short8*)&Bs_l[so + (wn0 + nf * 16 + fr) * 32 + quad * 8];
      }
#pragma unroll
      for (int mf = 0; mf < 2; ++mf)
#pragma unroll
        for (int nf = 0; nf < 2; ++nf) {
          acc[mf][nf] = __builtin_amdgcn_mfma_f32_16x16x32_bf16(ah[mf],  bh[nf],  acc[mf][nf], 0, 0, 0);
          acc[mf][nf] = __builtin_amdgcn_mfma_f32_16x16x32_bf16(ah[mf],  bl2[nf], acc[mf][nf], 0, 0, 0);
          acc[mf][nf] = __builtin_amdgcn_mfma_f32_16x16x32_bf16(al2[mf], bh[nf],  acc[mf][nf], 0, 0, 0);
        }
    }
  }

#pragma unroll
  for (int mf = 0; mf < 2; ++mf)
#pragma unroll
    for (int nf = 0; nf < 2; ++nf) {
      const int col = col0 + wn0 + nf * 16 + fr;
#pragma unroll
      for (int r = 0; r < 4; ++r) {
        const int row = row0 + wm0 + mf * 16 + quad * 4 + r;
        C[(size_t)row * D + col] = acc[mf][nf][r];
      }
    }
}

// ---------------------------------------------------------------------------
// (conv_out + conv_bias) -> LayerNorm -> ReLU -> bf16 hi/lo packed (row g=s+1).
// ---------------------------------------------------------------------------
__global__ __launch_bounds__(256) void ln_relu_pack_kernel(
    const float* __restrict__ X, const float* __restrict__ cb,
    const float* __restrict__ gam, const float* __restrict__ bet,
    ushort* __restrict__ th, ushort* __restrict__ tl) {
  const int wave = threadIdx.x >> 6;
  const int lane = threadIdx.x & 63;
  const int s = blockIdx.x * 4 + wave;
  const float4* xp = (const float4*)(X + (size_t)s * D);
  float4 a = xp[2 * lane];
  float4 b = xp[2 * lane + 1];
  const float4 ca  = ((const float4*)cb)[2 * lane];
  const float4 cb2 = ((const float4*)cb)[2 * lane + 1];
  float v[8] = {a.x + ca.x,  a.y + ca.y,  a.z + ca.z,  a.w + ca.w,
                b.x + cb2.x, b.y + cb2.y, b.z + cb2.z, b.w + cb2.w};
  float sum = 0.f;
#pragma unroll
  for (int i = 0; i < 8; ++i) sum += v[i];
#pragma unroll
  for (int off = 32; off > 0; off >>= 1) sum += __shfl_xor(sum, off);
  const float m = sum * (1.0f / D);
  float sq = 0.f;
#pragma unroll
  for (int i = 0; i < 8; ++i) { v[i] -= m; sq += v[i] * v[i]; }
#pragma unroll
  for (int off = 32; off > 0; off >>= 1) sq += __shfl_xor(sq, off);
  const float rs = rsqrtf(sq * (1.0f / D) + EPSLN);
  const float4 ga = ((const float4*)gam)[2 * lane];
  const float4 gb = ((const float4*)gam)[2 * lane + 1];
  const float4 ba = ((const float4*)bet)[2 * lane];
  const float4 bb = ((const float4*)bet)[2 * lane + 1];
  const float gg[8] = {ga.x, ga.y, ga.z, ga.w, gb.x, gb.y, gb.z, gb.w};
  const float bt[8] = {ba.x, ba.y, ba.z, ba.w, bb.x, bb.y, bb.z, bb.w};
  short8 h8, l8;
#pragma unroll
  for (int i = 0; i < 8; ++i) {
    float y = fmaxf(v[i] * rs * gg[i] + bt[i], 0.0f);
    ushort hi = f2bf(y);
    h8[i] = (short)hi;
    l8[i] = (short)f2bf(y - bf2f(hi));
  }
  const size_t base = ((size_t)(lane >> 2) * SP + (s + 1)) * 32 + (size_t)(lane & 3) * 8;
  *(short8*)(th + base) = h8;
  *(short8*)(tl + base) = l8;
}

// ---------------------------------------------------------------------------
// (conv2_out + bias) -> LN -> ReLU -> dot(lw) -> relu -> dur = floor(p + 0.5)
// ---------------------------------------------------------------------------
__global__ __launch_bounds__(256) void ln2_pred_kernel(
    const float* __restrict__ X, const float* __restrict__ cb,
    const float* __restrict__ gam, const float* __restrict__ bet,
    const float* __restrict__ lw, const float* __restrict__ lb,
    int* __restrict__ dur) {
  const int wave = threadIdx.x >> 6;
  const int lane = threadIdx.x & 63;
  const int s = blockIdx.x * 4 + wave;
  const float4* xp = (const float4*)(X + (size_t)s * D);
  float4 a = xp[2 * lane];
  float4 b = xp[2 * lane + 1];
  const float4 ca  = ((const float4*)cb)[2 * lane];
  const float4 cb2 = ((const float4*)cb)[2 * lane + 1];
  float v[8] = {a.x + ca.x,  a.y + ca.y,  a.z + ca.z,  a.w + ca.w,
                b.x + cb2.x, b.y + cb2.y, b.z + cb2.z, b.w + cb2.w};
  float sum = 0.f;
#pragma unroll
  for (int i = 0; i < 8; ++i) sum += v[i];
#pragma unroll
  for (int off = 32; off > 0; off >>= 1) sum += __shfl_xor(sum, off);
  const float m = sum * (1.0f / D);
  float sq = 0.f;
#pragma unroll
  for (int i = 0; i < 8; ++i) { v[i] -= m; sq += v[i] * v[i]; }
#pragma unroll
  for (int off = 32; off > 0; off >>= 1) sq += __shfl_xor(sq, off);
  const float rs = rsqrtf(sq * (1.0f / D) + EPSLN);
  const float4 ga = ((const float4*)gam)[2 * lane];
  const float4 gb = ((const float4*)gam)[2 * lane + 1];
  const float4 ba = ((const float4*)bet)[2 * lane];
  const float4 bb = ((const float4*)bet)[2 * lane + 1];
  const float gg[8] = {ga.x, ga.y, ga.z, ga.w, gb.x, gb.y, gb.z, gb.w};
  const float bt[8] = {ba.x, ba.y, ba.z, ba.w, bb.x, bb.y, bb.z, bb.w};
  const float4 w0 = ((const float4*)lw)[2 * lane];
  const float4 w1 = ((const float4*)lw)[2 * lane + 1];
  const float ww[8] = {w0.x, w0.y, w0.z, w0.w, w1.x, w1.y, w1.z, w1.w};
  float d = 0.f;
#pragma unroll
  for (int i = 0; i < 8; ++i) {
    float y = fmaxf(v[i] * rs * gg[i] + bt[i], 0.0f);
    d += y * ww[i];
  }
#pragma unroll
  for (int off = 32; off > 0; off >>= 1) d += __shfl_xor(d, off);
  if (lane == 0) {
    const float p = fmaxf(d + lb[0], 0.0f);
    dur[s] = (int)floorf(p + 0.5f);
  }
}

// ---------------------------------------------------------------------------
// Inclusive scan of S=4096 ints with ONE wave: 64 elems/lane serial, then
// 6-step shuffle scan of lane totals. Latency ~2 us.
// ---------------------------------------------------------------------------
__global__ __launch_bounds__(64) void scan_kernel(const int* __restrict__ dur,
                                                  int* __restrict__ cum) {
  const int lane = threadIdx.x;
  const int4* src = (const int4*)dur + (size_t)lane * 16;
  int4 v[16];
  int run = 0;
#pragma unroll
  for (int i = 0; i < 16; ++i) {
    int4 d = src[i];
    d.x += run; d.y += d.x; d.z += d.y; d.w += d.z;
    run = d.w;
    v[i] = d;
  }
  int sc = run;
#pragma unroll
  for (int off = 1; off < 64; off <<= 1) {
    const int n = __shfl_up(sc, off);
    if (lane >= off) sc += n;
  }
  const int base = sc - run;   // exclusive prefix of this lane's chunk
  int4* dst = (int4*)cum + (size_t)lane * 16;
#pragma unroll
  for (int i = 0; i < 16; ++i) {
    int4 d = v[i];
    d.x += base; d.y += base; d.z += base; d.w += base;
    dst[i] = d;
  }
}

// ---------------------------------------------------------------------------
// Length-regulate gather. 2 frames per 256-thread block.
// ---------------------------------------------------------------------------
__global__ __launch_bounds__(256) void gather_kernel(
    const float* __restrict__ enc, const int* __restrict__ cum,
    float* __restrict__ out0, float* __restrict__ out1) {
  const int half = threadIdx.x >> 7;
  const int d4   = (threadIdx.x & 127) << 2;
  const int t    = blockIdx.x * 2 + half;
  const int total = cum[S - 1];

  int lo = 0, hi = S;
  while (lo < hi) {
    const int mid = (lo + hi) >> 1;
    if (cum[mid] <= t) lo = mid + 1; else hi = mid;
  }
  const int idx = (lo < S) ? lo : (S - 1);

  float4 v = make_float4(0.f, 0.f, 0.f, 0.f);
  if (t < total) v = *(const float4*)(enc + (size_t)idx * D + d4);
  *(float4*)(out0 + (size_t)t * D + d4) = v;

  if ((threadIdx.x & 127) == 0) out1[t] = (float)(t + 1);
}

// ---------------------------------------------------------------------------
extern "C" void kernel_launch(void* const* d_in, const int* in_sizes, int n_in,
                              void* d_out, int out_size, void* d_ws, size_t ws_size,
                              hipStream_t stream) {
  const float* enc = (const float*)d_in[0];
  const float* w1  = (const float*)d_in[1];
  const float* cb1 = (const float*)d_in[2];
  const float* g1  = (const float*)d_in[3];
  const float* be1 = (const float*)d_in[4];
  const float* w2  = (const float*)d_in[5];
  const float* cb2 = (const float*)d_in[6];
  const float* g2  = (const float*)d_in[7];
  const float* be2 = (const float*)d_in[8];
  const float* lw  = (const float*)d_in[9];
  const float* lb  = (const float*)d_in[10];

  float* out0 = (float*)d_out;                 // [MAXOUT, D]
  float* out1 = out0 + (size_t)MAXOUT * D;     // [MAXOUT]

  const size_t NP = (size_t)NIT * SP * 32;     // packed activation elems
  const size_t NB = (size_t)NKT * D * 32;      // packed weight elems
  ushort* Xph = (ushort*)d_ws;
  ushort* Xpl = Xph + NP;
  ushort* T1h = Xpl + NP;
  ushort* T1l = T1h + NP;
  ushort* B1h = T1l + NP;
  ushort* B1l = B1h + NB;
  ushort* B2h = B1l + NB;
  ushort* B2l = B2h + NB;
  float*  t0  = (float*)(B2l + NB);            // S*D fp32
  int*   dur  = (int*)(t0 + (size_t)S * D);
  int*   cum  = dur + S;

  pack_all_kernel<<<NB0 + 2 * NB1 + NB3, 256, 0, stream>>>(
      enc, w1, w2, Xph, Xpl, B1h, B1l, B2h, B2l, T1h, T1l);
  gemm_mfma_kernel<<<dim3(S / 64, D / 64), 256, 0, stream>>>(Xph, Xpl, B1h, B1l, t0);
  ln_relu_pack_kernel<<<S / 4, 256, 0, stream>>>(t0, cb1, g1, be1, T1h, T1l);
  gemm_mfma_kernel<<<dim3(S / 64, D / 64), 256, 0, stream>>>(T1h, T1l, B2h, B2l, t0);
  ln2_pred_kernel<<<S / 4, 256, 0, stream>>>(t0, cb2, g2, be2, lw, lb, dur);
  scan_kernel<<<1, 64, 0, stream>>>(dur, cum);
  gather_kernel<<<MAXOUT / 2, 256, 0, stream>>>(enc, cum, out0, out1);
}